// Round 1
// baseline (6555.650 us; speedup 1.0000x reference)
//
#include <hip/hip_runtime.h>
#include <math.h>

// ---------------- constants ----------------
#define SEQ    256
#define NBATCH 8
#define CHN    512
#define NHEADS 8
#define HDIM   64
#define NTOK   2048          // SEQ * NBATCH
#define KCB    2048
#define NL     12

// ---------------- workspace layout (float offsets) ----------------
#define OFF_PE    0u          // 256*512
#define OFF_X     131072u     // 2048*512
#define OFF_QKV   1179648u    // 2048*1536
#define OFF_SC    4325376u    // 64*256*256
#define OFF_ATT   8519680u    // 2048*512
#define OFF_PROJ  9568256u    // 2048*512
#define OFF_HID   10616832u   // 2048*512
#define OFF_MEM   11665408u   // 2048*512
#define OFF_D     12713984u   // 2048*2048
#define OFF_P     16908288u   // 2048*2048
#define OFF_RN    21102592u   // 2048
#define OFF_CN    21104640u   // 2048
#define OFF_MAXI  21106688u   // 2048
#define OFF_CODES 21108736u   // 2048 (int)

// ---------------- output layout (float offsets) ----------------
#define OUT_DE    0u          // 8*512*16*16
#define OUT_CODES 1048576u    // 8*16*16
#define OUT_ZS    1050624u    // 256*8*512
#define OUT_ZQ    2099200u
#define OUT_SOFT  3147776u
#define OUT_CWT   4196352u    // 2048*512

__device__ __forceinline__ float gelu_exact(float x) {
  return 0.5f * x * (1.0f + erff(x * 0.70710678118654752440f));
}

// ---------------- positional encoding ----------------
__global__ __launch_bounds__(256) void k_pe(float* __restrict__ pe) {
  int idx = blockIdx.x * 256 + threadIdx.x;   // < 256*512
  int s = idx >> 9, c = idx & 511;
  int hh = s >> 4, ww = s & 15;
  int pos = (c < 256) ? hh : ww;
  int cc  = (c < 256) ? c  : c - 256;
  int i = cc >> 1;
  float dv = expf((float)(2 * i) * (-9.210340371976184f / 256.0f));
  float ang = (float)pos * dv;
  pe[idx] = (cc & 1) ? cosf(ang) : sinf(ang);
}

// x[(s*8+b)*512+c] = latents[b][c][hh][ww] + pe[s][c]
__global__ __launch_bounds__(256) void k_addpe_lat(const float* __restrict__ lat,
    const float* __restrict__ pe, float* __restrict__ x) {
  int idx = blockIdx.x * 256 + threadIdx.x;   // < 2048*512
  int r = idx >> 9, c = idx & 511;
  int s = r >> 3, b = r & 7;
  int hh = s >> 4, ww = s & 15;
  x[idx] = lat[((b * 512 + c) * 16 + hh) * 16 + ww] + pe[s * 512 + c];
}

// pq = zs + pe -> write to mem and x
__global__ __launch_bounds__(256) void k_pq(const float* __restrict__ pe,
    float* __restrict__ x, float* __restrict__ mem) {
  int idx = blockIdx.x * 256 + threadIdx.x;
  int r = idx >> 9, c = idx & 511;
  int s = r >> 3;
  float v = x[idx] + pe[s * 512 + c];
  mem[idx] = v; x[idx] = v;
}

// ---------------- generic NT GEMM ----------------
// C[M x N] (ldc) = alpha * A(MxK, lda=K) @ B(NxK, ldb=K)^T, with epilogue:
// EPI 0: none | 1: +bias[col] | 2: gelu(v+bias[col]) | 3: +rown[row]+coln[col]
#define MMA_BODY()                                                        \
  _Pragma("unroll")                                                       \
  for (int kk = 0; kk < 16; ++kk) {                                       \
    const float4 av = *(const float4*)&As[kk][ty * 4];                    \
    const float4 bv = *(const float4*)&Bs[kk][tx * 4];                    \
    const float aa[4] = {av.x, av.y, av.z, av.w};                         \
    const float bb[4] = {bv.x, bv.y, bv.z, bv.w};                         \
    _Pragma("unroll") for (int i = 0; i < 4; ++i)                         \
      _Pragma("unroll") for (int j = 0; j < 4; ++j)                       \
        acc[i][j] += aa[i] * bb[j];                                       \
  }

template <int EPI>
__global__ __launch_bounds__(256) void gemm_nt(
    const float* __restrict__ A, const float* __restrict__ B,
    float* __restrict__ C, const float* __restrict__ bias,
    const float* __restrict__ rown, const float* __restrict__ coln,
    int M, int N, int K, int ldc, float alpha) {
  __shared__ float As[16][68];
  __shared__ float Bs[16][68];
  int tid = threadIdx.x;
  int tx = tid & 15, ty = tid >> 4;
  int m0 = blockIdx.y * 64, n0 = blockIdx.x * 64;
  int lrow = tid >> 2;
  int lk = (tid & 3) * 4;
  const float* Al = A + (size_t)(m0 + lrow) * K + lk;
  const float* Bl = B + (size_t)(n0 + lrow) * K + lk;
  float acc[4][4] = {};
  for (int k0 = 0; k0 < K; k0 += 16) {
    float4 a = *(const float4*)(Al + k0);
    float4 b = *(const float4*)(Bl + k0);
    __syncthreads();
    As[lk + 0][lrow] = a.x; As[lk + 1][lrow] = a.y;
    As[lk + 2][lrow] = a.z; As[lk + 3][lrow] = a.w;
    Bs[lk + 0][lrow] = b.x; Bs[lk + 1][lrow] = b.y;
    Bs[lk + 2][lrow] = b.z; Bs[lk + 3][lrow] = b.w;
    __syncthreads();
    MMA_BODY();
  }
  int row = m0 + ty * 4, col = n0 + tx * 4;
#pragma unroll
  for (int i = 0; i < 4; ++i) {
    float4 o;
    float* po = (float*)&o;
#pragma unroll
    for (int j = 0; j < 4; ++j) {
      float v = acc[i][j] * alpha;
      if (EPI == 1 || EPI == 2) v += bias[col + j];
      if (EPI == 2) v = gelu_exact(v);
      if (EPI == 3) v += rown[row + i] + coln[col + j];
      po[j] = v;
    }
    *(float4*)&C[(size_t)(row + i) * ldc + col] = o;
  }
}

// ---------------- attention: scores = 0.125 * Q K^T (per b,h) ----------------
__global__ __launch_bounds__(256) void attn_scores(const float* __restrict__ qkv,
                                                   float* __restrict__ sc) {
  int z = blockIdx.z; int b = z >> 3, h = z & 7;
  const float* Q  = qkv + b * 1536 + h * 64;          // row stride 12288
  const float* Kp = qkv + b * 1536 + 512 + h * 64;
  float* Cp = sc + (size_t)z * 65536;                 // 256x256
  __shared__ float As[16][68];
  __shared__ float Bs[16][68];
  int tid = threadIdx.x;
  int tx = tid & 15, ty = tid >> 4;
  int m0 = blockIdx.y * 64, n0 = blockIdx.x * 64;
  int lrow = tid >> 2;
  int lk = (tid & 3) * 4;
  float acc[4][4] = {};
  for (int k0 = 0; k0 < 64; k0 += 16) {
    float4 a = *(const float4*)(Q  + (size_t)(m0 + lrow) * 12288 + k0 + lk);
    float4 b4 = *(const float4*)(Kp + (size_t)(n0 + lrow) * 12288 + k0 + lk);
    __syncthreads();
    As[lk + 0][lrow] = a.x;  As[lk + 1][lrow] = a.y;
    As[lk + 2][lrow] = a.z;  As[lk + 3][lrow] = a.w;
    Bs[lk + 0][lrow] = b4.x; Bs[lk + 1][lrow] = b4.y;
    Bs[lk + 2][lrow] = b4.z; Bs[lk + 3][lrow] = b4.w;
    __syncthreads();
    MMA_BODY();
  }
#pragma unroll
  for (int i = 0; i < 4; ++i) {
    float4 o = make_float4(acc[i][0] * 0.125f, acc[i][1] * 0.125f,
                           acc[i][2] * 0.125f, acc[i][3] * 0.125f);
    *(float4*)&Cp[(size_t)(m0 + ty * 4 + i) * 256 + n0 + tx * 4] = o;
  }
}

// softmax over last dim (256) of sc, one wave per row
__global__ __launch_bounds__(256) void attn_softmax(float* __restrict__ sc) {
  int row = blockIdx.x * 4 + (threadIdx.x >> 6);
  int lane = threadIdx.x & 63;
  float4* p = (float4*)(sc + (size_t)row * 256) + lane;
  float4 v = *p;
  float mx = fmaxf(fmaxf(v.x, v.y), fmaxf(v.z, v.w));
#pragma unroll
  for (int m = 32; m; m >>= 1) mx = fmaxf(mx, __shfl_xor(mx, m));
  v.x = expf(v.x - mx); v.y = expf(v.y - mx);
  v.z = expf(v.z - mx); v.w = expf(v.w - mx);
  float s = v.x + v.y + v.z + v.w;
#pragma unroll
  for (int m = 32; m; m >>= 1) s += __shfl_xor(s, m);
  float inv = 1.0f / s;
  v.x *= inv; v.y *= inv; v.z *= inv; v.w *= inv;
  *p = v;
}

// O[s, b, h*64+d] = sum_t P[z][s][t] * V[t, b, h*64+d]
__global__ __launch_bounds__(256) void attn_av(const float* __restrict__ sc,
    const float* __restrict__ qkv, float* __restrict__ out) {
  int z = blockIdx.z; int b = z >> 3, h = z & 7;
  const float* P = sc + (size_t)z * 65536;            // 256 x 256
  const float* V = qkv + b * 1536 + 1024 + h * 64;    // row stride 12288
  float* O = out + b * 512 + h * 64;                  // row stride 4096
  __shared__ float As[16][68];
  __shared__ float Bs[16][68];
  int tid = threadIdx.x;
  int tx = tid & 15, ty = tid >> 4;
  int m0 = blockIdx.y * 64;
  int lrow = tid >> 2;
  int lk = (tid & 3) * 4;
  int brow = tid >> 4, bcol = (tid & 15) * 4;
  float acc[4][4] = {};
  for (int k0 = 0; k0 < 256; k0 += 16) {
    float4 a = *(const float4*)(P + (size_t)(m0 + lrow) * 256 + k0 + lk);
    float4 b4 = *(const float4*)(V + (size_t)(k0 + brow) * 12288 + bcol);
    __syncthreads();
    As[lk + 0][lrow] = a.x; As[lk + 1][lrow] = a.y;
    As[lk + 2][lrow] = a.z; As[lk + 3][lrow] = a.w;
    *(float4*)&Bs[brow][bcol] = b4;
    __syncthreads();
    MMA_BODY();
  }
#pragma unroll
  for (int i = 0; i < 4; ++i) {
    float4 o = make_float4(acc[i][0], acc[i][1], acc[i][2], acc[i][3]);
    *(float4*)&O[(size_t)(m0 + ty * 4 + i) * 4096 + tx * 4] = o;
  }
}

// ---------------- residual + layernorm (in place on x) ----------------
__global__ __launch_bounds__(256) void k_ln(float* __restrict__ x,
    const float* __restrict__ delta, const float* __restrict__ w,
    const float* __restrict__ bb) {
  int r = blockIdx.x, tid = threadIdx.x;
  float* xr = x + (size_t)r * 512;
  const float* dr = delta + (size_t)r * 512;
  float2 v = *(const float2*)(xr + tid * 2);
  float2 dd = *(const float2*)(dr + tid * 2);
  v.x += dd.x; v.y += dd.y;
  float s = v.x + v.y, sq = v.x * v.x + v.y * v.y;
#pragma unroll
  for (int m = 32; m; m >>= 1) { s += __shfl_xor(s, m); sq += __shfl_xor(sq, m); }
  __shared__ float as_[4], aq_[4];
  if ((tid & 63) == 0) { as_[tid >> 6] = s; aq_[tid >> 6] = sq; }
  __syncthreads();
  s  = as_[0] + as_[1] + as_[2] + as_[3];
  sq = aq_[0] + aq_[1] + aq_[2] + aq_[3];
  float mean = s * (1.0f / 512.0f);
  float var  = sq * (1.0f / 512.0f) - mean * mean;
  float rstd = rsqrtf(var + 1e-5f);
  int c = tid * 2;
  float2 o;
  o.x = (v.x - mean) * rstd * w[c] + bb[c];
  o.y = (v.y - mean) * rstd * w[c + 1] + bb[c + 1];
  *(float2*)(xr + tid * 2) = o;
}

// ---------------- quantizer helpers ----------------
// codebook (512 x 2048) -> cw_t (2048 x 512)
__global__ __launch_bounds__(256) void k_transpose_cb(const float* __restrict__ in,
                                                      float* __restrict__ out) {
  __shared__ float t[32][33];
  int tx = threadIdx.x & 31, ty = threadIdx.x >> 5;
  int xi = blockIdx.x * 32 + tx;
  int yi = blockIdx.y * 32 + ty;
#pragma unroll
  for (int i = 0; i < 4; ++i) t[ty + i * 8][tx] = in[(size_t)(yi + i * 8) * 2048 + xi];
  __syncthreads();
  int xo = blockIdx.y * 32 + tx;
  int yo = blockIdx.x * 32 + ty;
#pragma unroll
  for (int i = 0; i < 4; ++i) out[(size_t)(yo + i * 8) * 512 + xo] = t[tx][ty + i * 8];
}

// row sum-of-squares, rows of length 512, 4 rows/block
__global__ __launch_bounds__(256) void k_rownorm(const float* __restrict__ x,
                                                 float* __restrict__ out) {
  int row = blockIdx.x * 4 + (threadIdx.x >> 6);
  int lane = threadIdx.x & 63;
  const float4* p = (const float4*)(x + (size_t)row * 512);
  float4 a = p[lane], b = p[lane + 64];
  float s = a.x * a.x + a.y * a.y + a.z * a.z + a.w * a.w +
            b.x * b.x + b.y * b.y + b.z * b.z + b.w * b.w;
#pragma unroll
  for (int m = 32; m; m >>= 1) s += __shfl_xor(s, m);
  if (lane == 0) out[row] = s;
}

// per-row (2048) argmin (first index) and max
__global__ __launch_bounds__(256) void k_rowminmax(const float* __restrict__ d,
    int* __restrict__ codes, float* __restrict__ maxi) {
  int r = blockIdx.x, tid = threadIdx.x;
  const float* row = d + (size_t)r * 2048;
  float minv = 1e30f; int mini = 0; float maxv = -1e30f;
#pragma unroll
  for (int k = 0; k < 8; ++k) {
    int c = tid + k * 256;
    float v = row[c];
    if (v < minv) { minv = v; mini = c; }
    maxv = fmaxf(maxv, v);
  }
#pragma unroll
  for (int m = 32; m; m >>= 1) {
    float ov = __shfl_xor(minv, m);
    int   oi = __shfl_xor(mini, m);
    if (ov < minv || (ov == minv && oi < mini)) { minv = ov; mini = oi; }
    maxv = fmaxf(maxv, __shfl_xor(maxv, m));
  }
  __shared__ float sv[4]; __shared__ int si[4]; __shared__ float sm[4];
  int w = tid >> 6;
  if ((tid & 63) == 0) { sv[w] = minv; si[w] = mini; sm[w] = maxv; }
  __syncthreads();
  if (tid == 0) {
    for (int i = 1; i < 4; ++i) {
      if (sv[i] < minv || (sv[i] == minv && si[i] < mini)) { minv = sv[i]; mini = si[i]; }
      maxv = fmaxf(maxv, sm[i]);
    }
    codes[r] = mini; maxi[r] = maxv;
  }
}

// p[r][j] = softmax_j(d[r][j] / maxi[r]); row max of d/maxi is exactly 1
__global__ __launch_bounds__(256) void k_qsoftmax(const float* __restrict__ d,
    const float* __restrict__ maxi, float* __restrict__ p) {
  int r = blockIdx.x, tid = threadIdx.x;
  const float4* dr = (const float4*)(d + (size_t)r * 2048);
  float4* pr = (float4*)(p + (size_t)r * 2048);
  float inv = 1.0f / maxi[r];
  float4 a = dr[tid], b = dr[tid + 256];
  float4 ea, eb;
  ea.x = expf(a.x * inv - 1.0f); ea.y = expf(a.y * inv - 1.0f);
  ea.z = expf(a.z * inv - 1.0f); ea.w = expf(a.w * inv - 1.0f);
  eb.x = expf(b.x * inv - 1.0f); eb.y = expf(b.y * inv - 1.0f);
  eb.z = expf(b.z * inv - 1.0f); eb.w = expf(b.w * inv - 1.0f);
  float s = ea.x + ea.y + ea.z + ea.w + eb.x + eb.y + eb.z + eb.w;
#pragma unroll
  for (int m = 32; m; m >>= 1) s += __shfl_xor(s, m);
  __shared__ float ss[4];
  if ((tid & 63) == 0) ss[tid >> 6] = s;
  __syncthreads();
  float sc = 1.0f / (ss[0] + ss[1] + ss[2] + ss[3]);
  ea.x *= sc; ea.y *= sc; ea.z *= sc; ea.w *= sc;
  eb.x *= sc; eb.y *= sc; eb.z *= sc; eb.w *= sc;
  pr[tid] = ea; pr[tid + 256] = eb;
}

__global__ __launch_bounds__(256) void k_zq(const float* __restrict__ cwt,
    const int* __restrict__ codes, float* __restrict__ zq) {
  int idx = blockIdx.x * 256 + threadIdx.x;
  int r = idx >> 9, c = idx & 511;
  zq[idx] = cwt[(size_t)codes[r] * 512 + c];
}

__global__ __launch_bounds__(256) void k_codes(const int* __restrict__ codes,
                                               float* __restrict__ out) {
  int idx = blockIdx.x * 256 + threadIdx.x;   // < 2048
  int b = idx >> 8, s = idx & 255;
  out[idx] = (float)codes[s * 8 + b];
}

// de[b][c][hh][ww] = y[(s*8+b)*512+c]
__global__ __launch_bounds__(256) void k_de(const float* __restrict__ x,
                                            float* __restrict__ out) {
  int idx = blockIdx.x * 256 + threadIdx.x;   // < 1048576
  int ww = idx & 15, hh = (idx >> 4) & 15;
  int c = (idx >> 8) & 511, b = idx >> 17;
  out[idx] = x[(size_t)((hh * 16 + ww) * 8 + b) * 512 + c];
}

// ---------------- host-side layer drivers ----------------
struct Bufs {
  float *pe, *x, *qkv, *sc, *att, *proj, *hid, *mem, *dm, *pm, *rn, *cn, *mx;
  int* codes;
};

static inline void self_attn(const Bufs& w, const float* qkvw, const float* qkvb,
                             const float* ow, const float* ob,
                             const float* lnw, const float* lnb, hipStream_t st) {
  gemm_nt<1><<<dim3(24, 32), 256, 0, st>>>(w.x, qkvw, w.qkv, qkvb, nullptr, nullptr,
                                           2048, 1536, 512, 1536, 1.0f);
  attn_scores<<<dim3(4, 4, 64), 256, 0, st>>>(w.qkv, w.sc);
  attn_softmax<<<4096, 256, 0, st>>>(w.sc);
  attn_av<<<dim3(1, 4, 64), 256, 0, st>>>(w.sc, w.qkv, w.att);
  gemm_nt<1><<<dim3(8, 32), 256, 0, st>>>(w.att, ow, w.proj, ob, nullptr, nullptr,
                                          2048, 512, 512, 512, 1.0f);
  k_ln<<<2048, 256, 0, st>>>(w.x, w.proj, lnw, lnb);
}

static inline void ffn_block(const Bufs& w, const float* f1w, const float* f1b,
                             const float* f2w, const float* f2b,
                             const float* lnw, const float* lnb, hipStream_t st) {
  gemm_nt<2><<<dim3(8, 32), 256, 0, st>>>(w.x, f1w, w.hid, f1b, nullptr, nullptr,
                                          2048, 512, 512, 512, 1.0f);
  gemm_nt<1><<<dim3(8, 32), 256, 0, st>>>(w.hid, f2w, w.proj, f2b, nullptr, nullptr,
                                          2048, 512, 512, 512, 1.0f);
  k_ln<<<2048, 256, 0, st>>>(w.x, w.proj, lnw, lnb);
}

static inline void cross_attn(const Bufs& w, const float* qkvw, const float* qkvb,
                              const float* ow, const float* ob,
                              const float* lnw, const float* lnb, hipStream_t st) {
  // q from x (cols 0..511 of qkv buf), k/v from mem (cols 512..1535)
  gemm_nt<1><<<dim3(8, 32), 256, 0, st>>>(w.x, qkvw, w.qkv, qkvb, nullptr, nullptr,
                                          2048, 512, 512, 1536, 1.0f);
  gemm_nt<1><<<dim3(16, 32), 256, 0, st>>>(w.mem, qkvw + 512 * 512, w.qkv + 512,
                                           qkvb + 512, nullptr, nullptr,
                                           2048, 1024, 512, 1536, 1.0f);
  attn_scores<<<dim3(4, 4, 64), 256, 0, st>>>(w.qkv, w.sc);
  attn_softmax<<<4096, 256, 0, st>>>(w.sc);
  attn_av<<<dim3(1, 4, 64), 256, 0, st>>>(w.sc, w.qkv, w.att);
  gemm_nt<1><<<dim3(8, 32), 256, 0, st>>>(w.att, ow, w.proj, ob, nullptr, nullptr,
                                          2048, 512, 512, 512, 1.0f);
  k_ln<<<2048, 256, 0, st>>>(w.x, w.proj, lnw, lnb);
}

extern "C" void kernel_launch(void* const* d_in, const int* in_sizes, int n_in,
                              void* d_out, int out_size, void* d_ws, size_t ws_size,
                              hipStream_t stream) {
  (void)in_sizes; (void)n_in; (void)out_size; (void)ws_size;
  const float* lat   = (const float*)d_in[0];
  const float* eqkvw = (const float*)d_in[1];
  const float* eqkvb = (const float*)d_in[2];
  const float* eow   = (const float*)d_in[3];
  const float* eob   = (const float*)d_in[4];
  const float* ef1w  = (const float*)d_in[5];
  const float* ef1b  = (const float*)d_in[6];
  const float* ef2w  = (const float*)d_in[7];
  const float* ef2b  = (const float*)d_in[8];
  const float* el1w  = (const float*)d_in[9];
  const float* el1b  = (const float*)d_in[10];
  const float* el2w  = (const float*)d_in[11];
  const float* el2b  = (const float*)d_in[12];
  const float* sqw   = (const float*)d_in[13];
  const float* sqb   = (const float*)d_in[14];
  const float* sow   = (const float*)d_in[15];
  const float* sob   = (const float*)d_in[16];
  const float* cqw   = (const float*)d_in[17];
  const float* cqb   = (const float*)d_in[18];
  const float* cow   = (const float*)d_in[19];
  const float* cob   = (const float*)d_in[20];
  const float* df1w  = (const float*)d_in[21];
  const float* df1b  = (const float*)d_in[22];
  const float* df2w  = (const float*)d_in[23];
  const float* df2b  = (const float*)d_in[24];
  const float* dl1w  = (const float*)d_in[25];
  const float* dl1b  = (const float*)d_in[26];
  const float* dl2w  = (const float*)d_in[27];
  const float* dl2b  = (const float*)d_in[28];
  const float* dl3w  = (const float*)d_in[29];
  const float* dl3b  = (const float*)d_in[30];
  const float* cb    = (const float*)d_in[31];

  float* ws  = (float*)d_ws;
  float* out = (float*)d_out;
  Bufs w;
  w.pe = ws + OFF_PE;  w.x  = ws + OFF_X;    w.qkv = ws + OFF_QKV;
  w.sc = ws + OFF_SC;  w.att = ws + OFF_ATT; w.proj = ws + OFF_PROJ;
  w.hid = ws + OFF_HID; w.mem = ws + OFF_MEM;
  w.dm = ws + OFF_D;   w.pm = ws + OFF_P;
  w.rn = ws + OFF_RN;  w.cn = ws + OFF_CN;   w.mx = ws + OFF_MAXI;
  w.codes = (int*)(ws + OFF_CODES);

  // ---- input embedding ----
  k_pe<<<512, 256, 0, stream>>>(w.pe);
  k_addpe_lat<<<4096, 256, 0, stream>>>(lat, w.pe, w.x);

  // ---- encoder ----
  for (int l = 0; l < NL; ++l) {
    self_attn(w, eqkvw + (size_t)l * 786432, eqkvb + l * 1536,
              eow + (size_t)l * 262144, eob + l * 512,
              el1w + l * 512, el1b + l * 512, stream);
    ffn_block(w, ef1w + (size_t)l * 262144, ef1b + l * 512,
              ef2w + (size_t)l * 262144, ef2b + l * 512,
              el2w + l * 512, el2b + l * 512, stream);
  }

  // ---- quantizer ----
  hipMemcpyAsync(out + OUT_ZS, w.x, (size_t)NTOK * 512 * 4,
                 hipMemcpyDeviceToDevice, stream);
  k_transpose_cb<<<dim3(64, 16), 256, 0, stream>>>(cb, out + OUT_CWT);
  k_rownorm<<<512, 256, 0, stream>>>(w.x, w.rn);
  k_rownorm<<<512, 256, 0, stream>>>(out + OUT_CWT, w.cn);
  gemm_nt<3><<<dim3(32, 32), 256, 0, stream>>>(w.x, out + OUT_CWT, w.dm, nullptr,
                                               w.rn, w.cn, 2048, 2048, 512, 2048, -2.0f);
  k_rowminmax<<<2048, 256, 0, stream>>>(w.dm, w.codes, w.mx);
  k_zq<<<4096, 256, 0, stream>>>(out + OUT_CWT, w.codes, out + OUT_ZQ);
  k_codes<<<8, 256, 0, stream>>>(w.codes, out + OUT_CODES);
  k_qsoftmax<<<2048, 256, 0, stream>>>(w.dm, w.mx, w.pm);
  gemm_nt<0><<<dim3(8, 32), 256, 0, stream>>>(w.pm, cb, out + OUT_SOFT, nullptr,
                                              nullptr, nullptr, 2048, 512, 2048, 512, 1.0f);

  // ---- decoder ----
  k_pq<<<4096, 256, 0, stream>>>(w.pe, w.x, w.mem);
  for (int l = 0; l < NL; ++l) {
    self_attn(w, sqw + (size_t)l * 786432, sqb + l * 1536,
              sow + (size_t)l * 262144, sob + l * 512,
              dl1w + l * 512, dl1b + l * 512, stream);
    cross_attn(w, cqw + (size_t)l * 786432, cqb + l * 1536,
               cow + (size_t)l * 262144, cob + l * 512,
               dl2w + l * 512, dl2b + l * 512, stream);
    ffn_block(w, df1w + (size_t)l * 262144, df1b + l * 512,
              df2w + (size_t)l * 262144, df2b + l * 512,
              dl3w + l * 512, dl3b + l * 512, stream);
  }

  // ---- outputs ----
  k_de<<<4096, 256, 0, stream>>>(w.x, out + OUT_DE);
}

// Round 2
// 5130.638 us; speedup vs baseline: 1.2777x; 1.2777x over previous
//
#include <hip/hip_runtime.h>
#include <math.h>

typedef short bf16x8 __attribute__((ext_vector_type(8)));
typedef float f32x4 __attribute__((ext_vector_type(4)));

// ---------------- constants ----------------
#define NTOK   2048
#define NL     12

// ---------------- workspace layout (float offsets) ----------------
#define OFF_PE    0u          // 256*512
#define OFF_X     131072u     // 2048*512
#define OFF_QKV   1179648u    // 2048*1536
#define OFF_SC    4325376u    // 64*256*256
#define OFF_ATT   8519680u    // 2048*512
#define OFF_PROJ  9568256u    // 2048*512
#define OFF_HID   10616832u   // 2048*512
#define OFF_MEM   11665408u   // 2048*512
#define OFF_D     12713984u   // 2048*2048
#define OFF_P     16908288u   // 2048*2048
#define OFF_RN    21102592u   // 2048
#define OFF_CN    21104640u   // 2048
#define OFF_MAXI  21106688u   // 2048
#define OFF_CODES 21108736u   // 2048 (int)
#define OFF_VT    21110784u   // 64*64*256 = 1048576

// ---------------- output layout (float offsets) ----------------
#define OUT_DE    0u
#define OUT_CODES 1048576u
#define OUT_ZS    1050624u
#define OUT_ZQ    2099200u
#define OUT_SOFT  3147776u
#define OUT_CWT   4196352u

__device__ __forceinline__ float gelu_exact(float x) {
  return 0.5f * x * (1.0f + erff(x * 0.70710678118654752440f));
}
__device__ __forceinline__ unsigned short f2bf(float x) {
  unsigned int u = __float_as_uint(x);
  return (unsigned short)((u + 0x7FFF + ((u >> 16) & 1)) >> 16);
}
__device__ __forceinline__ float bf2f(unsigned short h) {
  return __uint_as_float(((unsigned int)h) << 16);
}

// ---------------- positional encoding ----------------
__global__ __launch_bounds__(256) void k_pe(float* __restrict__ pe) {
  int idx = blockIdx.x * 256 + threadIdx.x;
  int s = idx >> 9, c = idx & 511;
  int hh = s >> 4, ww = s & 15;
  int pos = (c < 256) ? hh : ww;
  int cc  = (c < 256) ? c  : c - 256;
  int i = cc >> 1;
  float dv = expf((float)(2 * i) * (-9.210340371976184f / 256.0f));
  float ang = (float)pos * dv;
  pe[idx] = (cc & 1) ? cosf(ang) : sinf(ang);
}

__global__ __launch_bounds__(256) void k_addpe_lat(const float* __restrict__ lat,
    const float* __restrict__ pe, float* __restrict__ x) {
  int idx = blockIdx.x * 256 + threadIdx.x;
  int r = idx >> 9, c = idx & 511;
  int s = r >> 3, b = r & 7;
  int hh = s >> 4, ww = s & 15;
  x[idx] = lat[((b * 512 + c) * 16 + hh) * 16 + ww] + pe[s * 512 + c];
}

__global__ __launch_bounds__(256) void k_pq(const float* __restrict__ pe,
    float* __restrict__ x, float* __restrict__ mem) {
  int idx = blockIdx.x * 256 + threadIdx.x;
  int r = idx >> 9, c = idx & 511;
  int s = r >> 3;
  float v = x[idx] + pe[s * 512 + c];
  mem[idx] = v; x[idx] = v;
}

// ---------------- split-bf16 MFMA NT GEMM ----------------
// C[M x N] = alpha * A(MxK, lda) @ B(NxK, ldb)^T + epilogue, batched over z.
// A = Ahi+Alo, B = Bhi+Blo in bf16; acc += Ahi*Bhi + Ahi*Blo + Alo*Bhi (fp32 MFMA).
// EPI 0: none | 1: +bias[col] | 2: gelu(v+bias[col]) | 3: +rown[row]+coln[col]
// batch modes (z=blockIdx.z, b=z>>3, h=z&7):
//   0: base + z*stride | 1: base + b*1536 + h*64 | 2: base + b*512 + h*64
template <int TBM, int TBN, int EPI, int MA, int MB, int MC>
__global__ __launch_bounds__(256) void gemm_sp(
    const float* __restrict__ A, const float* __restrict__ B,
    float* __restrict__ C, const float* __restrict__ bias,
    const float* __restrict__ rown, const float* __restrict__ coln,
    int M, int N, int K, int lda, int ldb, int ldc,
    long sA, long sB, long sC, float alpha) {
  constexpr int MFR = TBM / 32, NFR = TBN / 32;
  __shared__ unsigned short Ah[TBM][40], Al[TBM][40];
  __shared__ unsigned short Bh[TBN][40], Bl[TBN][40];
  int tid = threadIdx.x;
  int z = blockIdx.z, zb = z >> 3, zh = z & 7;
  const float* Ag = A + ((MA == 0) ? (size_t)z * sA : (size_t)(zb * 1536 + zh * 64));
  const float* Bg = B + ((MB == 0) ? (size_t)z * sB : (size_t)(zb * 1536 + zh * 64));
  float* Cg = C + ((MC == 0) ? (size_t)z * sC
                             : (MC == 1) ? (size_t)(zb * 1536 + zh * 64)
                                         : (size_t)(zb * 512 + zh * 64));
  int m0 = blockIdx.y * TBM, n0 = blockIdx.x * TBN;
  int lane = tid & 63, w = tid >> 6, wr = w >> 1, wc = w & 1;
  int lr = lane & 15, kg = lane >> 4;

  f32x4 acc[MFR][NFR];
#pragma unroll
  for (int m = 0; m < MFR; ++m)
#pragma unroll
    for (int n = 0; n < NFR; ++n) acc[m][n] = (f32x4){0.f, 0.f, 0.f, 0.f};

  for (int k0 = 0; k0 < K; k0 += 32) {
    float4 va[TBM / 32], vb[TBN / 32];
#pragma unroll
    for (int i = 0; i < TBM / 32; ++i) {
      int idx = tid + i * 256; int row = idx >> 3, f4 = (idx & 7) * 4;
      va[i] = *(const float4*)(Ag + (size_t)(m0 + row) * lda + k0 + f4);
    }
#pragma unroll
    for (int i = 0; i < TBN / 32; ++i) {
      int idx = tid + i * 256; int row = idx >> 3, f4 = (idx & 7) * 4;
      vb[i] = *(const float4*)(Bg + (size_t)(n0 + row) * ldb + k0 + f4);
    }
    __syncthreads();
#pragma unroll
    for (int i = 0; i < TBM / 32; ++i) {
      int idx = tid + i * 256; int row = idx >> 3, f4 = (idx & 7) * 4;
      const float* pv = (const float*)&va[i];
      ushort4 hh, ll;
      hh.x = f2bf(pv[0]); ll.x = f2bf(pv[0] - bf2f(hh.x));
      hh.y = f2bf(pv[1]); ll.y = f2bf(pv[1] - bf2f(hh.y));
      hh.z = f2bf(pv[2]); ll.z = f2bf(pv[2] - bf2f(hh.z));
      hh.w = f2bf(pv[3]); ll.w = f2bf(pv[3] - bf2f(hh.w));
      *(ushort4*)&Ah[row][f4] = hh; *(ushort4*)&Al[row][f4] = ll;
    }
#pragma unroll
    for (int i = 0; i < TBN / 32; ++i) {
      int idx = tid + i * 256; int row = idx >> 3, f4 = (idx & 7) * 4;
      const float* pv = (const float*)&vb[i];
      ushort4 hh, ll;
      hh.x = f2bf(pv[0]); ll.x = f2bf(pv[0] - bf2f(hh.x));
      hh.y = f2bf(pv[1]); ll.y = f2bf(pv[1] - bf2f(hh.y));
      hh.z = f2bf(pv[2]); ll.z = f2bf(pv[2] - bf2f(hh.z));
      hh.w = f2bf(pv[3]); ll.w = f2bf(pv[3] - bf2f(hh.w));
      *(ushort4*)&Bh[row][f4] = hh; *(ushort4*)&Bl[row][f4] = ll;
    }
    __syncthreads();

    bf16x8 fah[MFR], fal[MFR], fbh[NFR], fbl[NFR];
#pragma unroll
    for (int m = 0; m < MFR; ++m) {
      fah[m] = *(const bf16x8*)&Ah[wr * (TBM / 2) + m * 16 + lr][kg * 8];
      fal[m] = *(const bf16x8*)&Al[wr * (TBM / 2) + m * 16 + lr][kg * 8];
    }
#pragma unroll
    for (int n = 0; n < NFR; ++n) {
      fbh[n] = *(const bf16x8*)&Bh[wc * (TBN / 2) + n * 16 + lr][kg * 8];
      fbl[n] = *(const bf16x8*)&Bl[wc * (TBN / 2) + n * 16 + lr][kg * 8];
    }
#pragma unroll
    for (int m = 0; m < MFR; ++m)
#pragma unroll
      for (int n = 0; n < NFR; ++n) {
        acc[m][n] = __builtin_amdgcn_mfma_f32_16x16x32_bf16(fah[m], fbl[n], acc[m][n], 0, 0, 0);
        acc[m][n] = __builtin_amdgcn_mfma_f32_16x16x32_bf16(fal[m], fbh[n], acc[m][n], 0, 0, 0);
        acc[m][n] = __builtin_amdgcn_mfma_f32_16x16x32_bf16(fah[m], fbh[n], acc[m][n], 0, 0, 0);
      }
  }

#pragma unroll
  for (int m = 0; m < MFR; ++m)
#pragma unroll
    for (int n = 0; n < NFR; ++n) {
      int cg = n0 + wc * (TBN / 2) + n * 16 + lr;
#pragma unroll
      for (int r = 0; r < 4; ++r) {
        int rg = m0 + wr * (TBM / 2) + m * 16 + kg * 4 + r;
        float v = acc[m][n][r] * alpha;
        if (EPI == 1 || EPI == 2) v += bias[cg];
        if (EPI == 2) v = gelu_exact(v);
        if (EPI == 3) v += rown[rg] + coln[cg];
        Cg[(size_t)rg * ldc + cg] = v;
      }
    }
}

// ---------------- V transpose: Vt[z][d][t] = qkv[t][1024 + h*64 + d] ----------------
__global__ __launch_bounds__(256) void k_vt(const float* __restrict__ qkv,
                                            float* __restrict__ vt) {
  int z = blockIdx.y, t0 = blockIdx.x * 64;
  int zb = z >> 3, zh = z & 7;
  const float* src = qkv + zb * 1536 + 1024 + zh * 64;
  float* dst = vt + (size_t)z * 16384;
  __shared__ float t[64][65];
  int ty = threadIdx.x >> 4, tx = threadIdx.x & 15;
#pragma unroll
  for (int i = 0; i < 4; ++i) {
    int tl = ty + i * 16;
    float4 v = *(const float4*)(src + (size_t)(t0 + tl) * 12288 + tx * 4);
    t[tl][tx * 4 + 0] = v.x; t[tl][tx * 4 + 1] = v.y;
    t[tl][tx * 4 + 2] = v.z; t[tl][tx * 4 + 3] = v.w;
  }
  __syncthreads();
#pragma unroll
  for (int i = 0; i < 4; ++i) {
    int d = ty + i * 16;
    float4 o = make_float4(t[tx * 4 + 0][d], t[tx * 4 + 1][d],
                           t[tx * 4 + 2][d], t[tx * 4 + 3][d]);
    *(float4*)(dst + (size_t)d * 256 + t0 + tx * 4) = o;
  }
}

// ---------------- softmax over last dim (256), one wave per row ----------------
__global__ __launch_bounds__(256) void attn_softmax(float* __restrict__ sc) {
  int row = blockIdx.x * 4 + (threadIdx.x >> 6);
  int lane = threadIdx.x & 63;
  float4* p = (float4*)(sc + (size_t)row * 256) + lane;
  float4 v = *p;
  float mx = fmaxf(fmaxf(v.x, v.y), fmaxf(v.z, v.w));
#pragma unroll
  for (int m = 32; m; m >>= 1) mx = fmaxf(mx, __shfl_xor(mx, m));
  v.x = expf(v.x - mx); v.y = expf(v.y - mx);
  v.z = expf(v.z - mx); v.w = expf(v.w - mx);
  float s = v.x + v.y + v.z + v.w;
#pragma unroll
  for (int m = 32; m; m >>= 1) s += __shfl_xor(s, m);
  float inv = 1.0f / s;
  v.x *= inv; v.y *= inv; v.z *= inv; v.w *= inv;
  *p = v;
}

// ---------------- residual + layernorm (in place on x) ----------------
__global__ __launch_bounds__(256) void k_ln(float* __restrict__ x,
    const float* __restrict__ delta, const float* __restrict__ w,
    const float* __restrict__ bb) {
  int r = blockIdx.x, tid = threadIdx.x;
  float* xr = x + (size_t)r * 512;
  const float* dr = delta + (size_t)r * 512;
  float2 v = *(const float2*)(xr + tid * 2);
  float2 dd = *(const float2*)(dr + tid * 2);
  v.x += dd.x; v.y += dd.y;
  float s = v.x + v.y, sq = v.x * v.x + v.y * v.y;
#pragma unroll
  for (int m = 32; m; m >>= 1) { s += __shfl_xor(s, m); sq += __shfl_xor(sq, m); }
  __shared__ float as_[4], aq_[4];
  if ((tid & 63) == 0) { as_[tid >> 6] = s; aq_[tid >> 6] = sq; }
  __syncthreads();
  s  = as_[0] + as_[1] + as_[2] + as_[3];
  sq = aq_[0] + aq_[1] + aq_[2] + aq_[3];
  float mean = s * (1.0f / 512.0f);
  float var  = sq * (1.0f / 512.0f) - mean * mean;
  float rstd = rsqrtf(var + 1e-5f);
  int c = tid * 2;
  float2 o;
  o.x = (v.x - mean) * rstd * w[c] + bb[c];
  o.y = (v.y - mean) * rstd * w[c + 1] + bb[c + 1];
  *(float2*)(xr + tid * 2) = o;
}

// ---------------- quantizer helpers ----------------
__global__ __launch_bounds__(256) void k_transpose_cb(const float* __restrict__ in,
                                                      float* __restrict__ out) {
  __shared__ float t[32][33];
  int tx = threadIdx.x & 31, ty = threadIdx.x >> 5;
  int xi = blockIdx.x * 32 + tx;
  int yi = blockIdx.y * 32 + ty;
#pragma unroll
  for (int i = 0; i < 4; ++i) t[ty + i * 8][tx] = in[(size_t)(yi + i * 8) * 2048 + xi];
  __syncthreads();
  int xo = blockIdx.y * 32 + tx;
  int yo = blockIdx.x * 32 + ty;
#pragma unroll
  for (int i = 0; i < 4; ++i) out[(size_t)(yo + i * 8) * 512 + xo] = t[tx][ty + i * 8];
}

__global__ __launch_bounds__(256) void k_rownorm(const float* __restrict__ x,
                                                 float* __restrict__ out) {
  int row = blockIdx.x * 4 + (threadIdx.x >> 6);
  int lane = threadIdx.x & 63;
  const float4* p = (const float4*)(x + (size_t)row * 512);
  float4 a = p[lane], b = p[lane + 64];
  float s = a.x * a.x + a.y * a.y + a.z * a.z + a.w * a.w +
            b.x * b.x + b.y * b.y + b.z * b.z + b.w * b.w;
#pragma unroll
  for (int m = 32; m; m >>= 1) s += __shfl_xor(s, m);
  if (lane == 0) out[row] = s;
}

__global__ __launch_bounds__(256) void k_rowminmax(const float* __restrict__ d,
    int* __restrict__ codes, float* __restrict__ maxi) {
  int r = blockIdx.x, tid = threadIdx.x;
  const float* row = d + (size_t)r * 2048;
  float minv = 1e30f; int mini = 0; float maxv = -1e30f;
#pragma unroll
  for (int k = 0; k < 8; ++k) {
    int c = tid + k * 256;
    float v = row[c];
    if (v < minv) { minv = v; mini = c; }
    maxv = fmaxf(maxv, v);
  }
#pragma unroll
  for (int m = 32; m; m >>= 1) {
    float ov = __shfl_xor(minv, m);
    int   oi = __shfl_xor(mini, m);
    if (ov < minv || (ov == minv && oi < mini)) { minv = ov; mini = oi; }
    maxv = fmaxf(maxv, __shfl_xor(maxv, m));
  }
  __shared__ float sv[4]; __shared__ int si[4]; __shared__ float sm[4];
  int w = tid >> 6;
  if ((tid & 63) == 0) { sv[w] = minv; si[w] = mini; sm[w] = maxv; }
  __syncthreads();
  if (tid == 0) {
    for (int i = 1; i < 4; ++i) {
      if (sv[i] < minv || (sv[i] == minv && si[i] < mini)) { minv = sv[i]; mini = si[i]; }
      maxv = fmaxf(maxv, sm[i]);
    }
    codes[r] = mini; maxi[r] = maxv;
  }
}

__global__ __launch_bounds__(256) void k_qsoftmax(const float* __restrict__ d,
    const float* __restrict__ maxi, float* __restrict__ p) {
  int r = blockIdx.x, tid = threadIdx.x;
  const float4* dr = (const float4*)(d + (size_t)r * 2048);
  float4* pr = (float4*)(p + (size_t)r * 2048);
  float inv = 1.0f / maxi[r];
  float4 a = dr[tid], b = dr[tid + 256];
  float4 ea, eb;
  ea.x = expf(a.x * inv - 1.0f); ea.y = expf(a.y * inv - 1.0f);
  ea.z = expf(a.z * inv - 1.0f); ea.w = expf(a.w * inv - 1.0f);
  eb.x = expf(b.x * inv - 1.0f); eb.y = expf(b.y * inv - 1.0f);
  eb.z = expf(b.z * inv - 1.0f); eb.w = expf(b.w * inv - 1.0f);
  float s = ea.x + ea.y + ea.z + ea.w + eb.x + eb.y + eb.z + eb.w;
#pragma unroll
  for (int m = 32; m; m >>= 1) s += __shfl_xor(s, m);
  __shared__ float ss[4];
  if ((tid & 63) == 0) ss[tid >> 6] = s;
  __syncthreads();
  float sc = 1.0f / (ss[0] + ss[1] + ss[2] + ss[3]);
  ea.x *= sc; ea.y *= sc; ea.z *= sc; ea.w *= sc;
  eb.x *= sc; eb.y *= sc; eb.z *= sc; eb.w *= sc;
  pr[tid] = ea; pr[tid + 256] = eb;
}

__global__ __launch_bounds__(256) void k_zq(const float* __restrict__ cwt,
    const int* __restrict__ codes, float* __restrict__ zq) {
  int idx = blockIdx.x * 256 + threadIdx.x;
  int r = idx >> 9, c = idx & 511;
  zq[idx] = cwt[(size_t)codes[r] * 512 + c];
}

__global__ __launch_bounds__(256) void k_codes(const int* __restrict__ codes,
                                               float* __restrict__ out) {
  int idx = blockIdx.x * 256 + threadIdx.x;
  int b = idx >> 8, s = idx & 255;
  out[idx] = (float)codes[s * 8 + b];
}

__global__ __launch_bounds__(256) void k_de(const float* __restrict__ x,
                                            float* __restrict__ out) {
  int idx = blockIdx.x * 256 + threadIdx.x;
  int ww = idx & 15, hh = (idx >> 4) & 15;
  int c = (idx >> 8) & 511, b = idx >> 17;
  out[idx] = x[(size_t)((hh * 16 + ww) * 8 + b) * 512 + c];
}

// ---------------- host-side layer drivers ----------------
struct Bufs {
  float *pe, *x, *qkv, *sc, *att, *proj, *hid, *mem, *dm, *pm, *rn, *cn, *mx, *vt;
  int* codes;
};

static inline void attn_core(const Bufs& w, hipStream_t st) {
  k_vt<<<dim3(4, 64), 256, 0, st>>>(w.qkv, w.vt);
  gemm_sp<64, 64, 0, 1, 1, 0><<<dim3(4, 4, 64), 256, 0, st>>>(
      w.qkv, w.qkv + 512, w.sc, nullptr, nullptr, nullptr,
      256, 256, 64, 12288, 12288, 256, 0, 0, 65536, 0.125f);
  attn_softmax<<<4096, 256, 0, st>>>(w.sc);
  gemm_sp<64, 64, 0, 0, 0, 2><<<dim3(1, 4, 64), 256, 0, st>>>(
      w.sc, w.vt, w.att, nullptr, nullptr, nullptr,
      256, 64, 256, 256, 256, 4096, 65536, 16384, 0, 1.0f);
}

static inline void self_attn(const Bufs& w, const float* qkvw, const float* qkvb,
                             const float* ow, const float* ob,
                             const float* lnw, const float* lnb, hipStream_t st) {
  gemm_sp<64, 64, 1, 0, 0, 0><<<dim3(24, 32), 256, 0, st>>>(
      w.x, qkvw, w.qkv, qkvb, nullptr, nullptr,
      2048, 1536, 512, 512, 512, 1536, 0, 0, 0, 1.0f);
  attn_core(w, st);
  gemm_sp<64, 64, 1, 0, 0, 0><<<dim3(8, 32), 256, 0, st>>>(
      w.att, ow, w.proj, ob, nullptr, nullptr,
      2048, 512, 512, 512, 512, 512, 0, 0, 0, 1.0f);
  k_ln<<<2048, 256, 0, st>>>(w.x, w.proj, lnw, lnb);
}

static inline void cross_attn(const Bufs& w, const float* qkvw, const float* qkvb,
                              const float* ow, const float* ob,
                              const float* lnw, const float* lnb, hipStream_t st) {
  gemm_sp<64, 64, 1, 0, 0, 0><<<dim3(8, 32), 256, 0, st>>>(
      w.x, qkvw, w.qkv, qkvb, nullptr, nullptr,
      2048, 512, 512, 512, 512, 1536, 0, 0, 0, 1.0f);
  gemm_sp<64, 64, 1, 0, 0, 0><<<dim3(16, 32), 256, 0, st>>>(
      w.mem, qkvw + 512 * 512, w.qkv + 512, qkvb + 512, nullptr, nullptr,
      2048, 1024, 512, 512, 512, 1536, 0, 0, 0, 1.0f);
  attn_core(w, st);
  gemm_sp<64, 64, 1, 0, 0, 0><<<dim3(8, 32), 256, 0, st>>>(
      w.att, ow, w.proj, ob, nullptr, nullptr,
      2048, 512, 512, 512, 512, 512, 0, 0, 0, 1.0f);
  k_ln<<<2048, 256, 0, st>>>(w.x, w.proj, lnw, lnb);
}

static inline void ffn_block(const Bufs& w, const float* f1w, const float* f1b,
                             const float* f2w, const float* f2b,
                             const float* lnw, const float* lnb, hipStream_t st) {
  gemm_sp<64, 64, 2, 0, 0, 0><<<dim3(8, 32), 256, 0, st>>>(
      w.x, f1w, w.hid, f1b, nullptr, nullptr,
      2048, 512, 512, 512, 512, 512, 0, 0, 0, 1.0f);
  gemm_sp<64, 64, 1, 0, 0, 0><<<dim3(8, 32), 256, 0, st>>>(
      w.hid, f2w, w.proj, f2b, nullptr, nullptr,
      2048, 512, 512, 512, 512, 512, 0, 0, 0, 1.0f);
  k_ln<<<2048, 256, 0, st>>>(w.x, w.proj, lnw, lnb);
}

extern "C" void kernel_launch(void* const* d_in, const int* in_sizes, int n_in,
                              void* d_out, int out_size, void* d_ws, size_t ws_size,
                              hipStream_t stream) {
  (void)in_sizes; (void)n_in; (void)out_size; (void)ws_size;
  const float* lat   = (const float*)d_in[0];
  const float* eqkvw = (const float*)d_in[1];
  const float* eqkvb = (const float*)d_in[2];
  const float* eow   = (const float*)d_in[3];
  const float* eob   = (const float*)d_in[4];
  const float* ef1w  = (const float*)d_in[5];
  const float* ef1b  = (const float*)d_in[6];
  const float* ef2w  = (const float*)d_in[7];
  const float* ef2b  = (const float*)d_in[8];
  const float* el1w  = (const float*)d_in[9];
  const float* el1b  = (const float*)d_in[10];
  const float* el2w  = (const float*)d_in[11];
  const float* el2b  = (const float*)d_in[12];
  const float* sqw   = (const float*)d_in[13];
  const float* sqb   = (const float*)d_in[14];
  const float* sow   = (const float*)d_in[15];
  const float* sob   = (const float*)d_in[16];
  const float* cqw   = (const float*)d_in[17];
  const float* cqb   = (const float*)d_in[18];
  const float* cow   = (const float*)d_in[19];
  const float* cob   = (const float*)d_in[20];
  const float* df1w  = (const float*)d_in[21];
  const float* df1b  = (const float*)d_in[22];
  const float* df2w  = (const float*)d_in[23];
  const float* df2b  = (const float*)d_in[24];
  const float* dl1w  = (const float*)d_in[25];
  const float* dl1b  = (const float*)d_in[26];
  const float* dl2w  = (const float*)d_in[27];
  const float* dl2b  = (const float*)d_in[28];
  const float* dl3w  = (const float*)d_in[29];
  const float* dl3b  = (const float*)d_in[30];
  const float* cb    = (const float*)d_in[31];

  float* ws  = (float*)d_ws;
  float* out = (float*)d_out;
  Bufs w;
  w.pe = ws + OFF_PE;  w.x  = ws + OFF_X;    w.qkv = ws + OFF_QKV;
  w.sc = ws + OFF_SC;  w.att = ws + OFF_ATT; w.proj = ws + OFF_PROJ;
  w.hid = ws + OFF_HID; w.mem = ws + OFF_MEM;
  w.dm = ws + OFF_D;   w.pm = ws + OFF_P;
  w.rn = ws + OFF_RN;  w.cn = ws + OFF_CN;   w.mx = ws + OFF_MAXI;
  w.vt = ws + OFF_VT;
  w.codes = (int*)(ws + OFF_CODES);

  // ---- input embedding ----
  k_pe<<<512, 256, 0, stream>>>(w.pe);
  k_addpe_lat<<<4096, 256, 0, stream>>>(lat, w.pe, w.x);

  // ---- encoder ----
  for (int l = 0; l < NL; ++l) {
    self_attn(w, eqkvw + (size_t)l * 786432, eqkvb + l * 1536,
              eow + (size_t)l * 262144, eob + l * 512,
              el1w + l * 512, el1b + l * 512, stream);
    ffn_block(w, ef1w + (size_t)l * 262144, ef1b + l * 512,
              ef2w + (size_t)l * 262144, ef2b + l * 512,
              el2w + l * 512, el2b + l * 512, stream);
  }

  // ---- quantizer ----
  hipMemcpyAsync(out + OUT_ZS, w.x, (size_t)NTOK * 512 * 4,
                 hipMemcpyDeviceToDevice, stream);
  k_transpose_cb<<<dim3(64, 16), 256, 0, stream>>>(cb, out + OUT_CWT);
  k_rownorm<<<512, 256, 0, stream>>>(w.x, w.rn);
  k_rownorm<<<512, 256, 0, stream>>>(out + OUT_CWT, w.cn);
  gemm_sp<128, 128, 3, 0, 0, 0><<<dim3(16, 16), 256, 0, stream>>>(
      w.x, out + OUT_CWT, w.dm, nullptr, w.rn, w.cn,
      2048, 2048, 512, 512, 512, 2048, 0, 0, 0, -2.0f);
  k_rowminmax<<<2048, 256, 0, stream>>>(w.dm, w.codes, w.mx);
  k_zq<<<4096, 256, 0, stream>>>(out + OUT_CWT, w.codes, out + OUT_ZQ);
  k_codes<<<8, 256, 0, stream>>>(w.codes, out + OUT_CODES);
  k_qsoftmax<<<2048, 256, 0, stream>>>(w.dm, w.mx, w.pm);
  gemm_sp<64, 64, 0, 0, 0, 0><<<dim3(8, 32), 256, 0, stream>>>(
      w.pm, cb, out + OUT_SOFT, nullptr, nullptr, nullptr,
      2048, 512, 2048, 2048, 2048, 512, 0, 0, 0, 1.0f);

  // ---- decoder ----
  k_pq<<<4096, 256, 0, stream>>>(w.pe, w.x, w.mem);
  for (int l = 0; l < NL; ++l) {
    self_attn(w, sqw + (size_t)l * 786432, sqb + l * 1536,
              sow + (size_t)l * 262144, sob + l * 512,
              dl1w + l * 512, dl1b + l * 512, stream);
    cross_attn(w, cqw + (size_t)l * 786432, cqb + l * 1536,
               cow + (size_t)l * 262144, cob + l * 512,
               dl2w + l * 512, dl2b + l * 512, stream);
    ffn_block(w, df1w + (size_t)l * 262144, df1b + l * 512,
              df2w + (size_t)l * 262144, df2b + l * 512,
              dl3w + l * 512, dl3b + l * 512, stream);
  }

  // ---- outputs ----
  k_de<<<4096, 256, 0, stream>>>(w.x, out + OUT_DE);
}

// Round 8
// 3029.574 us; speedup vs baseline: 2.1639x; 1.6935x over previous
//
#include <hip/hip_runtime.h>
#include <math.h>

typedef unsigned short u16;
typedef u16 u16x8 __attribute__((ext_vector_type(8)));
typedef short bf16x8 __attribute__((ext_vector_type(8)));
typedef float f32x4 __attribute__((ext_vector_type(4)));

#define NL 12

// ---------------- workspace layout (byte offsets), peak 65.6 MB ----------------
constexpr size_t B_PE    = 0;                          // 256*512 f32
constexpr size_t B_X     = B_PE   + 131072ull * 4;     // 2048*512 f32
constexpr size_t B_PROJ  = B_X    + 1048576ull * 4;    // 2048*512 f32 (delta)
constexpr size_t B_DM    = B_PROJ + 1048576ull * 4;    // 2048*2048 f32
constexpr size_t B_RN    = B_DM   + 4194304ull * 4;
constexpr size_t B_CN    = B_RN   + 2048ull * 4;
constexpr size_t B_MX    = B_CN   + 2048ull * 4;
constexpr size_t B_CODES = B_MX   + 2048ull * 4;
// activation bf16 hi/lo planes (ushort)
constexpr size_t B_XH    = B_CODES + 2048ull * 4;      // 2048*512 each
constexpr size_t B_XL    = B_XH   + 1048576ull * 2;
constexpr size_t B_QKVH  = B_XL   + 1048576ull * 2;    // 2048*1536
constexpr size_t B_QKVL  = B_QKVH + 3145728ull * 2;
constexpr size_t B_ATTH  = B_QKVL + 3145728ull * 2;    // 2048*512
constexpr size_t B_ATTL  = B_ATTH + 1048576ull * 2;
constexpr size_t B_HIDH  = B_ATTL + 1048576ull * 2;
constexpr size_t B_HIDL  = B_HIDH + 1048576ull * 2;
constexpr size_t B_MEMH  = B_HIDL + 1048576ull * 2;
constexpr size_t B_MEML  = B_MEMH + 1048576ull * 2;
// JIT weight pool: per-plane 2621440 el (QKV|OUT|F1|F2|CAQKV|CAOUT), 2 planes
constexpr size_t B_POOL  = B_MEML + 1048576ull * 2;    // 10485760 bytes
constexpr size_t B_END   = B_POOL + 2621440ull * 2 * 2; // = 65,568,768
// time-disjoint aliases (quantizer phase only; QKV/ATT/HID planes dead then)
constexpr size_t B_PMH   = B_QKVH;   // 2048*2048 u16 = 8388608 B (fits QKVH+QKVL)
constexpr size_t B_PML   = B_ATTH;   // 8388608 B = ATTH+ATTL+HIDH+HIDL exactly
constexpr size_t B_CWTH  = B_MEMH;   // cw_t planes (MEM written later by k_pq)
constexpr size_t B_CWTL  = B_MEML;
// pool element offsets (per plane)
constexpr size_t P_QKV   = 0;
constexpr size_t P_OUT   = 786432;
constexpr size_t P_F1    = 1048576;
constexpr size_t P_F2    = 1310720;
constexpr size_t P_CAQKV = 1572864;
constexpr size_t P_CAOUT = 2359296;
constexpr size_t P_PLANE = 2621440;  // L-plane offset

// ---------------- output layout (float offsets) ----------------
#define OUT_DE    0u
#define OUT_CODES 1048576u
#define OUT_ZS    1050624u
#define OUT_ZQ    2099200u
#define OUT_SOFT  3147776u
#define OUT_CWT   4196352u

__device__ __forceinline__ float gelu_exact(float x) {
  return 0.5f * x * (1.0f + erff(x * 0.70710678118654752440f));
}
// trunc-split: x == bf(h) + ~bf(l) to ~2^-16 relative
__device__ __forceinline__ void fsplit(float x, u16& h, u16& l) {
  unsigned u = __float_as_uint(x);
  h = (u16)(u >> 16);
  float hf = __uint_as_float(u & 0xFFFF0000u);
  l = (u16)(__float_as_uint(x - hf) >> 16);
}

// ---------------- weight conversion ----------------
__global__ __launch_bounds__(256) void k_cvt(const float* __restrict__ src,
    u16* __restrict__ h, u16* __restrict__ l) {
  int i = (blockIdx.x * 256 + threadIdx.x) * 4;
  float4 v = *(const float4*)&src[i];
  ushort4 hh, ll;
  fsplit(v.x, hh.x, ll.x); fsplit(v.y, hh.y, ll.y);
  fsplit(v.z, hh.z, ll.z); fsplit(v.w, hh.w, ll.w);
  *(ushort4*)&h[i] = hh; *(ushort4*)&l[i] = ll;
}

// per-layer JIT conversion into the pool. segments (element ranges):
// [0,786432) s0 | [786432,1048576) s1 | [1048576,1310720) s2 |
// [1310720,1572864) s3 | [1572864,2359296) s4 | [2359296,2621440) s5
__global__ __launch_bounds__(256) void k_cvt_layer(
    const float* __restrict__ s0, const float* __restrict__ s1,
    const float* __restrict__ s2, const float* __restrict__ s3,
    const float* __restrict__ s4, const float* __restrict__ s5,
    u16* __restrict__ ph, u16* __restrict__ pl) {
  int i = (blockIdx.x * 256 + threadIdx.x) * 4;
  const float* src; int off;
  if (i < 786432)       { src = s0; off = 0; }
  else if (i < 1048576) { src = s1; off = 786432; }
  else if (i < 1310720) { src = s2; off = 1048576; }
  else if (i < 1572864) { src = s3; off = 1310720; }
  else if (i < 2359296) { src = s4; off = 1572864; }
  else                  { src = s5; off = 2359296; }
  float4 v = *(const float4*)&src[i - off];
  ushort4 hh, ll;
  fsplit(v.x, hh.x, ll.x); fsplit(v.y, hh.y, ll.y);
  fsplit(v.z, hh.z, ll.z); fsplit(v.w, hh.w, ll.w);
  *(ushort4*)&ph[i] = hh; *(ushort4*)&pl[i] = ll;
}

// ---------------- positional encoding ----------------
__global__ __launch_bounds__(256) void k_pe(float* __restrict__ pe) {
  int idx = blockIdx.x * 256 + threadIdx.x;
  int s = idx >> 9, c = idx & 511;
  int hh = s >> 4, ww = s & 15;
  int pos = (c < 256) ? hh : ww;
  int cc  = (c < 256) ? c  : c - 256;
  int i = cc >> 1;
  float dv = expf((float)(2 * i) * (-9.210340371976184f / 256.0f));
  float ang = (float)pos * dv;
  pe[idx] = (cc & 1) ? cosf(ang) : sinf(ang);
}

__global__ __launch_bounds__(256) void k_addpe_lat(const float* __restrict__ lat,
    const float* __restrict__ pe, float* __restrict__ x,
    u16* __restrict__ xh, u16* __restrict__ xl) {
  int idx = blockIdx.x * 256 + threadIdx.x;
  int r = idx >> 9, c = idx & 511;
  int s = r >> 3, b = r & 7;
  int hh = s >> 4, ww = s & 15;
  float v = lat[((b * 512 + c) * 16 + hh) * 16 + ww] + pe[s * 512 + c];
  x[idx] = v;
  u16 h, l; fsplit(v, h, l); xh[idx] = h; xl[idx] = l;
}

__global__ __launch_bounds__(256) void k_pq(const float* __restrict__ pe,
    float* __restrict__ x, u16* __restrict__ xh, u16* __restrict__ xl,
    u16* __restrict__ mh, u16* __restrict__ ml) {
  int idx = blockIdx.x * 256 + threadIdx.x;
  int r = idx >> 9, c = idx & 511;
  int s = r >> 3;
  float v = x[idx] + pe[s * 512 + c];
  x[idx] = v;
  u16 h, l; fsplit(v, h, l);
  xh[idx] = h; xl[idx] = l; mh[idx] = h; ml[idx] = l;
}

// ---------------- split-bf16 NT GEMM on preconverted planes ----------------
// C[M x N] = alpha * (Ah+Al)(Bh+Bl)^T + epilogue. 64x64 tile, BK=64.
// EPI 0: none | 1: +bias[col] | 2: gelu(v+bias[col]) | 3: +rown[row]+coln[col]
// OM  0: fp32 C | 1: bf16 hi/lo planes
template <int EPI, int OM>
__global__ __launch_bounds__(256) void gemm_bb(
    const u16* __restrict__ Ah, const u16* __restrict__ Al,
    const u16* __restrict__ Bh, const u16* __restrict__ Bl,
    float* __restrict__ Cf, u16* __restrict__ Ch, u16* __restrict__ Cl,
    const float* __restrict__ bias, const float* __restrict__ rown,
    const float* __restrict__ coln,
    int K, int lda, int ldb, int ldc, float alpha) {
  __shared__ u16 Ahs[64 * 72], Als[64 * 72], Bhs[64 * 72], Bls[64 * 72];
  int tid = threadIdx.x;
  int m0 = blockIdx.y * 64, n0 = blockIdx.x * 64;
  int lane = tid & 63, w = tid >> 6, wr = w >> 1, wc = w & 1;
  int lr = lane & 15, kg = lane >> 4;
  int srow = tid >> 3, sk = (tid & 7) * 8;
  f32x4 acc[2][2];
#pragma unroll
  for (int m = 0; m < 2; ++m)
#pragma unroll
    for (int n = 0; n < 2; ++n) acc[m][n] = (f32x4){0.f, 0.f, 0.f, 0.f};

  for (int kb = 0; kb < K; kb += 64) {
    u16x8 ah[2], al[2], bh[2], bl[2];
#pragma unroll
    for (int i = 0; i < 2; ++i) {
      int row = srow + i * 32;
      size_t ga = (size_t)(m0 + row) * lda + kb + sk;
      size_t gb = (size_t)(n0 + row) * ldb + kb + sk;
      ah[i] = *(const u16x8*)&Ah[ga]; al[i] = *(const u16x8*)&Al[ga];
      bh[i] = *(const u16x8*)&Bh[gb]; bl[i] = *(const u16x8*)&Bl[gb];
    }
    __syncthreads();
#pragma unroll
    for (int i = 0; i < 2; ++i) {
      int o = (srow + i * 32) * 72 + sk;
      *(u16x8*)&Ahs[o] = ah[i]; *(u16x8*)&Als[o] = al[i];
      *(u16x8*)&Bhs[o] = bh[i]; *(u16x8*)&Bls[o] = bl[i];
    }
    __syncthreads();
#pragma unroll
    for (int kk = 0; kk < 2; ++kk) {
      bf16x8 fah[2], fal[2], fbh[2], fbl[2];
      int kc = kk * 32 + kg * 8;
#pragma unroll
      for (int m = 0; m < 2; ++m) {
        int o = (wr * 32 + m * 16 + lr) * 72 + kc;
        fah[m] = *(const bf16x8*)&Ahs[o];
        fal[m] = *(const bf16x8*)&Als[o];
      }
#pragma unroll
      for (int n = 0; n < 2; ++n) {
        int o = (wc * 32 + n * 16 + lr) * 72 + kc;
        fbh[n] = *(const bf16x8*)&Bhs[o];
        fbl[n] = *(const bf16x8*)&Bls[o];
      }
#pragma unroll
      for (int m = 0; m < 2; ++m)
#pragma unroll
        for (int n = 0; n < 2; ++n) {
          acc[m][n] = __builtin_amdgcn_mfma_f32_16x16x32_bf16(fah[m], fbl[n], acc[m][n], 0, 0, 0);
          acc[m][n] = __builtin_amdgcn_mfma_f32_16x16x32_bf16(fal[m], fbh[n], acc[m][n], 0, 0, 0);
          acc[m][n] = __builtin_amdgcn_mfma_f32_16x16x32_bf16(fah[m], fbh[n], acc[m][n], 0, 0, 0);
        }
    }
  }
#pragma unroll
  for (int m = 0; m < 2; ++m)
#pragma unroll
    for (int n = 0; n < 2; ++n) {
      int cg = n0 + wc * 32 + n * 16 + lr;
#pragma unroll
      for (int r = 0; r < 4; ++r) {
        int rg = m0 + wr * 32 + m * 16 + kg * 4 + r;
        float v = acc[m][n][r] * alpha;
        if (EPI == 1 || EPI == 2) v += bias[cg];
        if (EPI == 2) v = gelu_exact(v);
        if (EPI == 3) v += rown[rg] + coln[cg];
        size_t o = (size_t)rg * ldc + cg;
        if (OM == 0) Cf[o] = v;
        else { u16 h, l; fsplit(v, h, l); Ch[o] = h; Cl[o] = l; }
      }
    }
}

// ---------------- fused attention ----------------
// grid (4 qblocks, 64 z); z = b*8+h. qkv planes row stride 1536, token row s*8+b.
__global__ __launch_bounds__(256) void attn_fused(
    const u16* __restrict__ Ph, const u16* __restrict__ Pl,
    u16* __restrict__ Oh, u16* __restrict__ Ol) {
  __shared__ u16 KP[2][16384];   // K (256x64, swz) then P (64x256, swz)
  __shared__ u16 VS[2][4096];    // V tile transposed (64d x 64t, swz)
  int z = blockIdx.y, b = z >> 3, h = z & 7;
  size_t zoff = (size_t)b * 1536 + h * 64;
  int m0 = blockIdx.x * 64;
  int tid = threadIdx.x, lane = tid & 63, w = tid >> 6;
  int lr = lane & 15, kg = lane >> 4;

  // ---- stage K into LDS (hi/lo), XOR-swizzled ----
#pragma unroll
  for (int i = 0; i < 8; ++i) {
    int row = (tid >> 3) + i * 32;
    int c0 = (tid & 7) * 8;
    size_t g = (size_t)row * 12288 + zoff + 512 + c0;
    u16x8 vh = *(const u16x8*)&Ph[g];
    u16x8 vl = *(const u16x8*)&Pl[g];
    int idx = (row * 64 + c0) ^ ((row & 7) << 3);
    *(u16x8*)&KP[0][idx] = vh;
    *(u16x8*)&KP[1][idx] = vl;
  }
  // ---- Q fragments (direct from global planes) ----
  bf16x8 qh[2], ql[2];
  int sr = m0 + w * 16 + lr;
#pragma unroll
  for (int kk = 0; kk < 2; ++kk) {
    size_t g = (size_t)sr * 12288 + zoff + kk * 32 + kg * 8;
    qh[kk] = *(const bf16x8*)&Ph[g];
    ql[kk] = *(const bf16x8*)&Pl[g];
  }
  __syncthreads();

  // ---- S = Q K^T (raw, scale folded into softmax) ----
  f32x4 accs[16];
#pragma unroll
  for (int n = 0; n < 16; ++n) accs[n] = (f32x4){0.f, 0.f, 0.f, 0.f};
#pragma unroll
  for (int n = 0; n < 16; ++n) {
#pragma unroll
    for (int kk = 0; kk < 2; ++kk) {
      int ki = ((n * 16 + lr) * 64 + kk * 32 + kg * 8) ^ ((lr & 7) << 3);
      bf16x8 kh = *(const bf16x8*)&KP[0][ki];
      bf16x8 kl = *(const bf16x8*)&KP[1][ki];
      accs[n] = __builtin_amdgcn_mfma_f32_16x16x32_bf16(qh[kk], kl, accs[n], 0, 0, 0);
      accs[n] = __builtin_amdgcn_mfma_f32_16x16x32_bf16(ql[kk], kh, accs[n], 0, 0, 0);
      accs[n] = __builtin_amdgcn_mfma_f32_16x16x32_bf16(qh[kk], kh, accs[n], 0, 0, 0);
    }
  }
  // ---- wave-parallel softmax in registers (rows: kg*4+r; cols: n*16+lr) ----
#pragma unroll
  for (int r = 0; r < 4; ++r) {
    float mx = accs[0][r];
#pragma unroll
    for (int n = 1; n < 16; ++n) mx = fmaxf(mx, accs[n][r]);
#pragma unroll
    for (int mk = 1; mk < 16; mk <<= 1) mx = fmaxf(mx, __shfl_xor(mx, mk));
    float sum = 0.f;
#pragma unroll
    for (int n = 0; n < 16; ++n) {
      float p = __expf((accs[n][r] - mx) * 0.125f);
      accs[n][r] = p; sum += p;
    }
#pragma unroll
    for (int mk = 1; mk < 16; mk <<= 1) sum += __shfl_xor(sum, mk);
    float inv = 1.0f / sum;
#pragma unroll
    for (int n = 0; n < 16; ++n) accs[n][r] *= inv;
  }
  __syncthreads();   // everyone done reading K; region becomes P

  // ---- write P (hi/lo) to LDS; stage V tile 0 ----
#pragma unroll
  for (int n = 0; n < 16; ++n)
#pragma unroll
    for (int r = 0; r < 4; ++r) {
      int roww = w * 16 + kg * 4 + r;
      int idx = (roww * 256 + n * 16 + lr) ^ ((roww & 7) << 3);
      u16 hh, ll; fsplit(accs[n][r], hh, ll);
      KP[0][idx] = hh; KP[1][idx] = ll;
    }
#define STAGE_V(tv)                                                          \
  do {                                                                       \
    _Pragma("unroll")                                                        \
    for (int pass = 0; pass < 2; ++pass) {                                   \
      int tl = (tid >> 3) + pass * 32;                                       \
      int c0 = (tid & 7) * 8;                                                \
      size_t g = (size_t)((tv) * 64 + tl) * 12288 + zoff + 1024 + c0;        \
      u16x8 vh = *(const u16x8*)&Ph[g];                                      \
      u16x8 vl = *(const u16x8*)&Pl[g];                                      \
      _Pragma("unroll")                                                      \
      for (int j = 0; j < 8; ++j) {                                          \
        int d = c0 + j;                                                      \
        int idx = (d * 64 + tl) ^ ((d & 7) << 3);                            \
        VS[0][idx] = vh[j]; VS[1][idx] = vl[j];                              \
      }                                                                      \
    }                                                                        \
  } while (0)
  STAGE_V(0);

  // ---- O = P V ----
  f32x4 acco[4];
#pragma unroll
  for (int nb = 0; nb < 4; ++nb) acco[nb] = (f32x4){0.f, 0.f, 0.f, 0.f};
  for (int tv = 0; tv < 4; ++tv) {
    __syncthreads();
#pragma unroll
    for (int ks = 0; ks < 2; ++ks) {
      int pi = ((w * 16 + lr) * 256 + tv * 64 + ks * 32 + kg * 8) ^ ((lr & 7) << 3);
      bf16x8 ph = *(const bf16x8*)&KP[0][pi];
      bf16x8 pl = *(const bf16x8*)&KP[1][pi];
#pragma unroll
      for (int nb = 0; nb < 4; ++nb) {
        int vi = ((nb * 16 + lr) * 64 + ks * 32 + kg * 8) ^ ((lr & 7) << 3);
        bf16x8 vh = *(const bf16x8*)&VS[0][vi];
        bf16x8 vl = *(const bf16x8*)&VS[1][vi];
        acco[nb] = __builtin_amdgcn_mfma_f32_16x16x32_bf16(ph, vl, acco[nb], 0, 0, 0);
        acco[nb] = __builtin_amdgcn_mfma_f32_16x16x32_bf16(pl, vh, acco[nb], 0, 0, 0);
        acco[nb] = __builtin_amdgcn_mfma_f32_16x16x32_bf16(ph, vh, acco[nb], 0, 0, 0);
      }
    }
    __syncthreads();
    if (tv == 0) STAGE_V(1);
    else if (tv == 1) STAGE_V(2);
    else if (tv == 2) STAGE_V(3);
  }
  // ---- epilogue: O -> att planes ----
#pragma unroll
  for (int nb = 0; nb < 4; ++nb)
#pragma unroll
    for (int r = 0; r < 4; ++r) {
      int srow = m0 + w * 16 + kg * 4 + r;
      size_t o = (size_t)(srow * 8 + b) * 512 + h * 64 + nb * 16 + lr;
      u16 hh, ll; fsplit(acco[nb][r], hh, ll);
      Oh[o] = hh; Ol[o] = ll;
    }
}

// ---------------- residual + layernorm (fp32 x in place, + planes) ----------------
__global__ __launch_bounds__(256) void k_ln(float* __restrict__ x,
    const float* __restrict__ delta, const float* __restrict__ w,
    const float* __restrict__ bb, u16* __restrict__ xh, u16* __restrict__ xl) {
  int r = blockIdx.x, tid = threadIdx.x;
  float* xr = x + (size_t)r * 512;
  const float* dr = delta + (size_t)r * 512;
  float2 v = *(const float2*)(xr + tid * 2);
  float2 dd = *(const float2*)(dr + tid * 2);
  v.x += dd.x; v.y += dd.y;
  float s = v.x + v.y, sq = v.x * v.x + v.y * v.y;
#pragma unroll
  for (int m = 32; m; m >>= 1) { s += __shfl_xor(s, m); sq += __shfl_xor(sq, m); }
  __shared__ float as_[4], aq_[4];
  if ((tid & 63) == 0) { as_[tid >> 6] = s; aq_[tid >> 6] = sq; }
  __syncthreads();
  s  = as_[0] + as_[1] + as_[2] + as_[3];
  sq = aq_[0] + aq_[1] + aq_[2] + aq_[3];
  float mean = s * (1.0f / 512.0f);
  float var  = sq * (1.0f / 512.0f) - mean * mean;
  float rstd = rsqrtf(var + 1e-5f);
  int c = tid * 2;
  float2 o;
  o.x = (v.x - mean) * rstd * w[c] + bb[c];
  o.y = (v.y - mean) * rstd * w[c + 1] + bb[c + 1];
  *(float2*)(xr + tid * 2) = o;
  size_t pi = (size_t)r * 512 + c;
  u16 hh, ll;
  fsplit(o.x, hh, ll); xh[pi] = hh; xl[pi] = ll;
  fsplit(o.y, hh, ll); xh[pi + 1] = hh; xl[pi + 1] = ll;
}

// ---------------- quantizer helpers ----------------
__global__ __launch_bounds__(256) void k_transpose_cb(const float* __restrict__ in,
    float* __restrict__ out, u16* __restrict__ oh, u16* __restrict__ ol) {
  __shared__ float t[32][33];
  int tx = threadIdx.x & 31, ty = threadIdx.x >> 5;
  int xi = blockIdx.x * 32 + tx;
  int yi = blockIdx.y * 32 + ty;
#pragma unroll
  for (int i = 0; i < 4; ++i) t[ty + i * 8][tx] = in[(size_t)(yi + i * 8) * 2048 + xi];
  __syncthreads();
  int xo = blockIdx.y * 32 + tx;
  int yo = blockIdx.x * 32 + ty;
#pragma unroll
  for (int i = 0; i < 4; ++i) {
    float v = t[tx][ty + i * 8];
    size_t o = (size_t)(yo + i * 8) * 512 + xo;
    out[o] = v;
    u16 hh, ll; fsplit(v, hh, ll); oh[o] = hh; ol[o] = ll;
  }
}

__global__ __launch_bounds__(256) void k_rownorm(const float* __restrict__ x,
                                                 float* __restrict__ out) {
  int row = blockIdx.x * 4 + (threadIdx.x >> 6);
  int lane = threadIdx.x & 63;
  const float4* p = (const float4*)(x + (size_t)row * 512);
  float4 a = p[lane], b = p[lane + 64];
  float s = a.x * a.x + a.y * a.y + a.z * a.z + a.w * a.w +
            b.x * b.x + b.y * b.y + b.z * b.z + b.w * b.w;
#pragma unroll
  for (int m = 32; m; m >>= 1) s += __shfl_xor(s, m);
  if (lane == 0) out[row] = s;
}

__global__ __launch_bounds__(256) void k_rowminmax(const float* __restrict__ d,
    int* __restrict__ codes, float* __restrict__ maxi) {
  int r = blockIdx.x, tid = threadIdx.x;
  const float* row = d + (size_t)r * 2048;
  float minv = 1e30f; int mini = 0; float maxv = -1e30f;
#pragma unroll
  for (int k = 0; k < 8; ++k) {
    int c = tid + k * 256;
    float v = row[c];
    if (v < minv) { minv = v; mini = c; }
    maxv = fmaxf(maxv, v);
  }
#pragma unroll
  for (int m = 32; m; m >>= 1) {
    float ov = __shfl_xor(minv, m);
    int   oi = __shfl_xor(mini, m);
    if (ov < minv || (ov == minv && oi < mini)) { minv = ov; mini = oi; }
    maxv = fmaxf(maxv, __shfl_xor(maxv, m));
  }
  __shared__ float sv[4]; __shared__ int si[4]; __shared__ float sm[4];
  int w = tid >> 6;
  if ((tid & 63) == 0) { sv[w] = minv; si[w] = mini; sm[w] = maxv; }
  __syncthreads();
  if (tid == 0) {
    for (int i = 1; i < 4; ++i) {
      if (sv[i] < minv || (sv[i] == minv && si[i] < mini)) { minv = sv[i]; mini = si[i]; }
      maxv = fmaxf(maxv, sm[i]);
    }
    codes[r] = mini; maxi[r] = maxv;
  }
}

__global__ __launch_bounds__(256) void k_qsoftmax(const float* __restrict__ d,
    const float* __restrict__ maxi, u16* __restrict__ ph, u16* __restrict__ pl) {
  int r = blockIdx.x, tid = threadIdx.x;
  const float4* dr = (const float4*)(d + (size_t)r * 2048);
  float inv = 1.0f / maxi[r];
  float4 a = dr[tid], b = dr[tid + 256];
  float4 ea, eb;
  ea.x = __expf(a.x * inv - 1.0f); ea.y = __expf(a.y * inv - 1.0f);
  ea.z = __expf(a.z * inv - 1.0f); ea.w = __expf(a.w * inv - 1.0f);
  eb.x = __expf(b.x * inv - 1.0f); eb.y = __expf(b.y * inv - 1.0f);
  eb.z = __expf(b.z * inv - 1.0f); eb.w = __expf(b.w * inv - 1.0f);
  float s = ea.x + ea.y + ea.z + ea.w + eb.x + eb.y + eb.z + eb.w;
#pragma unroll
  for (int m = 32; m; m >>= 1) s += __shfl_xor(s, m);
  __shared__ float ss[4];
  if ((tid & 63) == 0) ss[tid >> 6] = s;
  __syncthreads();
  float sc = 1.0f / (ss[0] + ss[1] + ss[2] + ss[3]);
  size_t base = (size_t)r * 2048;
  ushort4 hh, ll;
  fsplit(ea.x * sc, hh.x, ll.x); fsplit(ea.y * sc, hh.y, ll.y);
  fsplit(ea.z * sc, hh.z, ll.z); fsplit(ea.w * sc, hh.w, ll.w);
  *(ushort4*)&ph[base + tid * 4] = hh; *(ushort4*)&pl[base + tid * 4] = ll;
  fsplit(eb.x * sc, hh.x, ll.x); fsplit(eb.y * sc, hh.y, ll.y);
  fsplit(eb.z * sc, hh.z, ll.z); fsplit(eb.w * sc, hh.w, ll.w);
  *(ushort4*)&ph[base + (tid + 256) * 4] = hh;
  *(ushort4*)&pl[base + (tid + 256) * 4] = ll;
}

__global__ __launch_bounds__(256) void k_zq(const float* __restrict__ cwt,
    const int* __restrict__ codes, float* __restrict__ zq) {
  int idx = blockIdx.x * 256 + threadIdx.x;
  int r = idx >> 9, c = idx & 511;
  zq[idx] = cwt[(size_t)codes[r] * 512 + c];
}

__global__ __launch_bounds__(256) void k_codes(const int* __restrict__ codes,
                                               float* __restrict__ out) {
  int idx = blockIdx.x * 256 + threadIdx.x;
  int b = idx >> 8, s = idx & 255;
  out[idx] = (float)codes[s * 8 + b];
}

__global__ __launch_bounds__(256) void k_de(const float* __restrict__ x,
                                            float* __restrict__ out) {
  int idx = blockIdx.x * 256 + threadIdx.x;
  int ww = idx & 15, hh = (idx >> 4) & 15;
  int c = (idx >> 8) & 511, b = idx >> 17;
  out[idx] = x[(size_t)((hh * 16 + ww) * 8 + b) * 512 + c];
}

// ---------------- host-side drivers ----------------
struct WS {
  char* base;
  float* f(size_t o) const { return (float*)(base + o); }
  u16*   u(size_t o) const { return (u16*)(base + o); }
  int*   i(size_t o) const { return (int*)(base + o); }
};

extern "C" void kernel_launch(void* const* d_in, const int* in_sizes, int n_in,
                              void* d_out, int out_size, void* d_ws, size_t ws_size,
                              hipStream_t stream) {
  (void)in_sizes; (void)n_in; (void)out_size; (void)ws_size;
  const float* lat   = (const float*)d_in[0];
  const float* eqkvw = (const float*)d_in[1];
  const float* eqkvb = (const float*)d_in[2];
  const float* eow   = (const float*)d_in[3];
  const float* eob   = (const float*)d_in[4];
  const float* ef1w  = (const float*)d_in[5];
  const float* ef1b  = (const float*)d_in[6];
  const float* ef2w  = (const float*)d_in[7];
  const float* ef2b  = (const float*)d_in[8];
  const float* el1w  = (const float*)d_in[9];
  const float* el1b  = (const float*)d_in[10];
  const float* el2w  = (const float*)d_in[11];
  const float* el2b  = (const float*)d_in[12];
  const float* sqw   = (const float*)d_in[13];
  const float* sqb   = (const float*)d_in[14];
  const float* sow   = (const float*)d_in[15];
  const float* sob   = (const float*)d_in[16];
  const float* cqw   = (const float*)d_in[17];
  const float* cqb   = (const float*)d_in[18];
  const float* cow   = (const float*)d_in[19];
  const float* cob   = (const float*)d_in[20];
  const float* df1w  = (const float*)d_in[21];
  const float* df1b  = (const float*)d_in[22];
  const float* df2w  = (const float*)d_in[23];
  const float* df2b  = (const float*)d_in[24];
  const float* dl1w  = (const float*)d_in[25];
  const float* dl1b  = (const float*)d_in[26];
  const float* dl2w  = (const float*)d_in[27];
  const float* dl2b  = (const float*)d_in[28];
  const float* dl3w  = (const float*)d_in[29];
  const float* dl3b  = (const float*)d_in[30];
  const float* cb    = (const float*)d_in[31];

  WS ws{(char*)d_ws};
  float* out = (float*)d_out;

  u16 *xh = ws.u(B_XH), *xl = ws.u(B_XL);
  u16 *qh = ws.u(B_QKVH), *ql = ws.u(B_QKVL);
  u16 *ath = ws.u(B_ATTH), *atl = ws.u(B_ATTL);
  u16 *hh = ws.u(B_HIDH), *hl = ws.u(B_HIDL);
  u16 *poolH = ws.u(B_POOL), *poolL = ws.u(B_POOL) + P_PLANE;
  float* xf = ws.f(B_X);
  float* pj = ws.f(B_PROJ);

  // ---- input embedding ----
  k_pe<<<512, 256, 0, stream>>>(ws.f(B_PE));
  k_addpe_lat<<<4096, 256, 0, stream>>>(lat, ws.f(B_PE), xf, xh, xl);

  auto self_attn = [&](const float* qb, const float* ob,
                       const float* lw, const float* lb) {
    gemm_bb<1, 1><<<dim3(24, 32), 256, 0, stream>>>(
        xh, xl, poolH + P_QKV, poolL + P_QKV, nullptr, qh, ql, qb,
        nullptr, nullptr, 512, 512, 512, 1536, 1.0f);
    attn_fused<<<dim3(4, 64), 256, 0, stream>>>(qh, ql, ath, atl);
    gemm_bb<1, 0><<<dim3(8, 32), 256, 0, stream>>>(
        ath, atl, poolH + P_OUT, poolL + P_OUT, pj, nullptr, nullptr, ob,
        nullptr, nullptr, 512, 512, 512, 512, 1.0f);
    k_ln<<<2048, 256, 0, stream>>>(xf, pj, lw, lb, xh, xl);
  };
  auto ffn_block = [&](const float* b1, const float* b2,
                       const float* lw, const float* lb) {
    gemm_bb<2, 1><<<dim3(8, 32), 256, 0, stream>>>(
        xh, xl, poolH + P_F1, poolL + P_F1, nullptr, hh, hl, b1,
        nullptr, nullptr, 512, 512, 512, 512, 1.0f);
    gemm_bb<1, 0><<<dim3(8, 32), 256, 0, stream>>>(
        hh, hl, poolH + P_F2, poolL + P_F2, pj, nullptr, nullptr, b2,
        nullptr, nullptr, 512, 512, 512, 512, 1.0f);
    k_ln<<<2048, 256, 0, stream>>>(xf, pj, lw, lb, xh, xl);
  };

  // ---- encoder (JIT weight conversion per layer) ----
  for (int l = 0; l < NL; ++l) {
    const float* q = eqkvw + (size_t)l * 786432;
    k_cvt_layer<<<1536, 256, 0, stream>>>(
        q, eow + (size_t)l * 262144, ef1w + (size_t)l * 262144,
        ef2w + (size_t)l * 262144, q, q, poolH, poolL);
    self_attn(eqkvb + l * 1536, eob + l * 512, el1w + l * 512, el1b + l * 512);
    ffn_block(ef1b + l * 512, ef2b + l * 512, el2w + l * 512, el2b + l * 512);
  }

  // ---- quantizer (PM planes alias QKV/ATT/HID; cw_t planes alias MEM;
  //      cb planes in pool — all time-disjoint) ----
  (void)hipMemcpyAsync(out + OUT_ZS, xf, 1048576ull * 4,
                       hipMemcpyDeviceToDevice, stream);
  k_cvt<<<1024, 256, 0, stream>>>(cb, poolH, poolL);
  k_transpose_cb<<<dim3(64, 16), 256, 0, stream>>>(cb, out + OUT_CWT,
                                                   ws.u(B_CWTH), ws.u(B_CWTL));
  k_rownorm<<<512, 256, 0, stream>>>(xf, ws.f(B_RN));
  k_rownorm<<<512, 256, 0, stream>>>(out + OUT_CWT, ws.f(B_CN));
  gemm_bb<3, 0><<<dim3(32, 32), 256, 0, stream>>>(
      xh, xl, ws.u(B_CWTH), ws.u(B_CWTL), ws.f(B_DM), nullptr, nullptr,
      nullptr, ws.f(B_RN), ws.f(B_CN), 512, 512, 512, 2048, -2.0f);
  k_rowminmax<<<2048, 256, 0, stream>>>(ws.f(B_DM), ws.i(B_CODES), ws.f(B_MX));
  k_zq<<<4096, 256, 0, stream>>>(out + OUT_CWT, ws.i(B_CODES), out + OUT_ZQ);
  k_codes<<<8, 256, 0, stream>>>(ws.i(B_CODES), out + OUT_CODES);
  k_qsoftmax<<<2048, 256, 0, stream>>>(ws.f(B_DM), ws.f(B_MX),
                                       ws.u(B_PMH), ws.u(B_PML));
  gemm_bb<0, 0><<<dim3(8, 32), 256, 0, stream>>>(
      ws.u(B_PMH), ws.u(B_PML), poolH, poolL, out + OUT_SOFT,
      nullptr, nullptr, nullptr, nullptr, nullptr, 2048, 2048, 2048, 512, 1.0f);

  // ---- decoder ----
  k_pq<<<4096, 256, 0, stream>>>(ws.f(B_PE), xf, xh, xl,
                                 ws.u(B_MEMH), ws.u(B_MEML));
  for (int l = 0; l < NL; ++l) {
    k_cvt_layer<<<2560, 256, 0, stream>>>(
        sqw + (size_t)l * 786432, sow + (size_t)l * 262144,
        df1w + (size_t)l * 262144, df2w + (size_t)l * 262144,
        cqw + (size_t)l * 786432, cow + (size_t)l * 262144, poolH, poolL);
    self_attn(sqb + l * 1536, sob + l * 512, dl1w + l * 512, dl1b + l * 512);
    // cross attention
    gemm_bb<1, 1><<<dim3(8, 32), 256, 0, stream>>>(
        xh, xl, poolH + P_CAQKV, poolL + P_CAQKV, nullptr, qh, ql,
        cqb + l * 1536, nullptr, nullptr, 512, 512, 512, 1536, 1.0f);
    gemm_bb<1, 1><<<dim3(16, 32), 256, 0, stream>>>(
        ws.u(B_MEMH), ws.u(B_MEML), poolH + P_CAQKV + 262144,
        poolL + P_CAQKV + 262144, nullptr, qh + 512, ql + 512,
        cqb + l * 1536 + 512, nullptr, nullptr, 512, 512, 512, 1536, 1.0f);
    attn_fused<<<dim3(4, 64), 256, 0, stream>>>(qh, ql, ath, atl);
    gemm_bb<1, 0><<<dim3(8, 32), 256, 0, stream>>>(
        ath, atl, poolH + P_CAOUT, poolL + P_CAOUT, pj, nullptr, nullptr,
        cob + l * 512, nullptr, nullptr, 512, 512, 512, 512, 1.0f);
    k_ln<<<2048, 256, 0, stream>>>(xf, pj, dl2w + l * 512, dl2b + l * 512, xh, xl);
    ffn_block(df1b + l * 512, df2b + l * 512, dl3w + l * 512, dl3b + l * 512);
  }

  // ---- outputs ----
  k_de<<<4096, 256, 0, stream>>>(xf, out + OUT_DE);
}